// Round 5
// baseline (111.015 us; speedup 1.0000x reference)
//
#include <hip/hip_runtime.h>
#include <hip/hip_bf16.h>

// SelfAttention (B=4, C=64, N=4096, CQ=8), fp32 in/out.
// K1 proj (single x pass, 20 dots/thread, s-loaded weights):
//   Q -> compact bf16 [b][n][8] PRE-SCALED by log2(e); K -> compact bf16
//   [b][n][8]; V -> bf16 TILED [b][m>>5][64c][m&31] (4 KB tiles).
// K2 attn (no LDS in loop): S^T = Kperm^T*Q via mfma_16x16x32_bf16 where
//   lane q16 loads K row 8*(q16>>2)+(q16&3) -- this row permutation makes
//   the exp'd C-fragment IDENTICAL to the B-operand fragment of PV
//   (O^T[c][n] = V^T * P^T), so the C->A transform costs zero instructions.
//   Unnormalized exp accumulate (|S|<~20: no max subtraction), per-lane
//   row-sum l (division is lane-local in epilogue), m split across 8 waves,
//   two-stage cross-wave (O,l) LDS reduction, out = gamma*O/l + x.

typedef __attribute__((ext_vector_type(8))) short short8;
typedef __attribute__((ext_vector_type(4))) float f32x4;
typedef unsigned short ushort_t;

#define NSEQ 4096
#define LOG2E 1.4426950408889634f

__device__ __forceinline__ unsigned pk_bf16(float lo, float hi) {
  union { __hip_bfloat16 b; unsigned short u; } cl, ch;
  cl.b = __float2bfloat16(lo);
  ch.b = __float2bfloat16(hi);
  return (unsigned)cl.u | ((unsigned)ch.u << 16);
}

__global__ __launch_bounds__(256) void proj_kernel(
    const float* __restrict__ x,
    const float* __restrict__ Wq, const float* __restrict__ bq,
    const float* __restrict__ Wk, const float* __restrict__ bk,
    const float* __restrict__ Wv, const float* __restrict__ bv,
    ushort_t* __restrict__ Qb, ushort_t* __restrict__ Kb,
    ushort_t* __restrict__ Vb)
{
  const int tid  = threadIdx.x;
  const int lane = tid & 63;
  const int w    = __builtin_amdgcn_readfirstlane(tid >> 6);  // 0..3
  const int blk  = blockIdx.x;
  const int b    = blk >> 6;
  const int n    = (blk & 63) * 64 + lane;

  const float* xb = x + (size_t)(b * 64) * NSEQ + n;

  // 16 V channels per wave
  const int cv0 = w * 16;
  float av[16];
#pragma unroll
  for (int j = 0; j < 16; ++j) av[j] = bv[cv0 + j];

  // 4 q-or-k channels per wave (w 0,1 -> q; w 2,3 -> k)
  const bool isq = (w < 2);
  const int qkb  = (w & 1) * 4;
  const float* Wr = isq ? Wq : Wk;
  const float* br = isq ? bq : bk;
  float aqk[4];
#pragma unroll
  for (int j = 0; j < 4; ++j) aqk[j] = br[qkb + j];

  // single pass over x (k-chunked; weights come through s_loads)
#pragma unroll
  for (int kc = 0; kc < 64; kc += 8) {
    float xv[8];
#pragma unroll
    for (int i = 0; i < 8; ++i) xv[i] = xb[(size_t)(kc + i) * NSEQ];
#pragma unroll
    for (int i = 0; i < 8; ++i) {
      const float xk = xv[i];
#pragma unroll
      for (int j = 0; j < 16; ++j) av[j] += Wv[(cv0 + j) * 64 + kc + i] * xk;
#pragma unroll
      for (int j = 0; j < 4; ++j) aqk[j] += Wr[(qkb + j) * 64 + kc + i] * xk;
    }
  }

  // V tiled store: tile (b, n>>5), row c, col n&31
  union { __hip_bfloat16 h; ushort_t u; } cv;
  ushort_t* vt = Vb + ((size_t)(b * 128 + (n >> 5)) * 64 + cv0) * 32 + (n & 31);
#pragma unroll
  for (int j = 0; j < 16; ++j) {
    cv.h = __float2bfloat16(av[j]);
    vt[j * 32] = cv.u;
  }

  // q/k store: 4 contiguous bf16 = one 8B store. Q pre-scaled by log2(e)
  // so attn's exp is a bare v_exp_f32.
  if (isq) {
#pragma unroll
    for (int j = 0; j < 4; ++j) aqk[j] *= LOG2E;
  }
  union { unsigned u[2]; ulong1 l; } pkd;
  pkd.u[0] = pk_bf16(aqk[0], aqk[1]);
  pkd.u[1] = pk_bf16(aqk[2], aqk[3]);
  ushort_t* qk = (isq ? Qb : Kb) + ((size_t)(b * NSEQ + n)) * 8 + qkb;
  *(ulong1*)qk = pkd.l;
}

__global__ __launch_bounds__(512, 4) void attn_kernel(
    const ushort_t* __restrict__ Qb, const ushort_t* __restrict__ Kb,
    const ushort_t* __restrict__ Vb, const float* __restrict__ x,
    const float* __restrict__ gamma, float* __restrict__ out)
{
  __shared__ float buf[4][64][36];   // staged (O,l) cross-wave reduction, 36 KB

  const int tid  = threadIdx.x;
  const int wave = __builtin_amdgcn_readfirstlane(tid >> 6);   // 0..7
  const int lane = tid & 63;
  const int q16  = lane & 15;
  const int quad = lane >> 4;
  const int blk  = blockIdx.x;
  const int b    = blk >> 7;
  const int n0   = (blk & 127) << 5;   // block's 32 queries
  const int mbase = wave << 9;         // this wave's 512-m range

  // Q B-frags (k>=8 zeroed so compact K loads raw: garbage*0 = 0)
  const short8 z8 = {0, 0, 0, 0, 0, 0, 0, 0};
  short8 qfA = *(const short8*)(Qb + ((size_t)(b * NSEQ + n0 + q16)) * 8);
  short8 qfB = *(const short8*)(Qb + ((size_t)(b * NSEQ + n0 + 16 + q16)) * 8);
  if (quad != 0) { qfA = z8; qfB = z8; }

  // K A-frag with the magic row permutation: lane q16 -> row 8*(q16>>2)+(q16&3)
  // => exp'd S^T C-frag IS the PV B-frag (k = 8*quad+j <-> m = 8*quad+j).
  const int mperm = 8 * (q16 >> 2) + (q16 & 3);
  const char* kbase = (const char*)(Kb + ((size_t)(b * NSEQ + mbase + mperm)) * 8);
  // V A-frag (V^T): A[row=c=q16][k=m=quad*8+j] from tiled [64c][32m] 4KB tiles
  const char* vbase = (const char*)(Vb + ((size_t)(b * 128 + (mbase >> 5)) * 64) * 32);
  const int voff = q16 * 64 + quad * 16;

  // accumulators: aXj = O^T tile, D[c = 16j+4*quad+r][n = q16 (+16 for B)]
  f32x4 aA0 = {0.f, 0.f, 0.f, 0.f};
  f32x4 aA1 = aA0, aA2 = aA0, aA3 = aA0;
  f32x4 aB0 = aA0, aB1 = aA0, aB2 = aA0, aB3 = aA0;
  float lA = 0.f, lB = 0.f;

  short8 kf0 = *(const short8*)(kbase);          // rows {8q..8q+3} block
  short8 kf1 = *(const short8*)(kbase + 64);     // rows {8q+4..8q+7} block
  short8 vf0 = *(const short8*)(vbase + voff);
  short8 vf1 = *(const short8*)(vbase + voff + 1024);
  short8 vf2 = *(const short8*)(vbase + voff + 2048);
  short8 vf3 = *(const short8*)(vbase + voff + 3072);

#pragma unroll 2
  for (int t = 0; t < 16; ++t) {
    const int tn = (t + 1 < 16) ? (t + 1) : 15;   // clamped prefetch
    const size_t ko = (size_t)tn * 512;           // 32 K rows * 16 B
    const size_t vo = (size_t)tn * 4096 + voff;   // next 4 KB V tile
    short8 nk0 = *(const short8*)(kbase + ko);
    short8 nk1 = *(const short8*)(kbase + ko + 64);
    short8 nv0 = *(const short8*)(vbase + vo);
    short8 nv1 = *(const short8*)(vbase + vo + 1024);
    short8 nv2 = *(const short8*)(vbase + vo + 2048);
    short8 nv3 = *(const short8*)(vbase + vo + 3072);

    // S^T in log2 domain (Q pre-scaled): D[mperm][n]
    const f32x4 z = {0.f, 0.f, 0.f, 0.f};
    f32x4 s0 = __builtin_amdgcn_mfma_f32_16x16x32_bf16(kf0, qfA, z, 0, 0, 0);
    f32x4 s1 = __builtin_amdgcn_mfma_f32_16x16x32_bf16(kf1, qfA, z, 0, 0, 0);
    f32x4 s2 = __builtin_amdgcn_mfma_f32_16x16x32_bf16(kf0, qfB, z, 0, 0, 0);
    f32x4 s3 = __builtin_amdgcn_mfma_f32_16x16x32_bf16(kf1, qfB, z, 0, 0, 0);

    // unnormalized numerators; lane (quad q, n) holds m = 8q..8q+7
    float pA0 = __builtin_amdgcn_exp2f(s0[0]);
    float pA1 = __builtin_amdgcn_exp2f(s0[1]);
    float pA2 = __builtin_amdgcn_exp2f(s0[2]);
    float pA3 = __builtin_amdgcn_exp2f(s0[3]);
    float pA4 = __builtin_amdgcn_exp2f(s1[0]);
    float pA5 = __builtin_amdgcn_exp2f(s1[1]);
    float pA6 = __builtin_amdgcn_exp2f(s1[2]);
    float pA7 = __builtin_amdgcn_exp2f(s1[3]);
    float pB0 = __builtin_amdgcn_exp2f(s2[0]);
    float pB1 = __builtin_amdgcn_exp2f(s2[1]);
    float pB2 = __builtin_amdgcn_exp2f(s2[2]);
    float pB3 = __builtin_amdgcn_exp2f(s2[3]);
    float pB4 = __builtin_amdgcn_exp2f(s3[0]);
    float pB5 = __builtin_amdgcn_exp2f(s3[1]);
    float pB6 = __builtin_amdgcn_exp2f(s3[2]);
    float pB7 = __builtin_amdgcn_exp2f(s3[3]);
    lA += ((pA0 + pA1) + (pA2 + pA3)) + ((pA4 + pA5) + (pA6 + pA7));
    lB += ((pB0 + pB1) + (pB2 + pB3)) + ((pB4 + pB5) + (pB6 + pB7));

    // pack pairs: result IS the PV B-frag B[k=8*quad+j][n] -- no movement
    union { unsigned u[4]; short8 s; } uA, uB;
    uA.u[0] = pk_bf16(pA0, pA1); uA.u[1] = pk_bf16(pA2, pA3);
    uA.u[2] = pk_bf16(pA4, pA5); uA.u[3] = pk_bf16(pA6, pA7);
    uB.u[0] = pk_bf16(pB0, pB1); uB.u[1] = pk_bf16(pB2, pB3);
    uB.u[2] = pk_bf16(pB4, pB5); uB.u[3] = pk_bf16(pB6, pB7);
    const short8 pfA = uA.s;
    const short8 pfB = uB.s;

    // O^T[c][n] += V^T[c][m] * P^T[m][n]
    aA0 = __builtin_amdgcn_mfma_f32_16x16x32_bf16(vf0, pfA, aA0, 0, 0, 0);
    aA1 = __builtin_amdgcn_mfma_f32_16x16x32_bf16(vf1, pfA, aA1, 0, 0, 0);
    aA2 = __builtin_amdgcn_mfma_f32_16x16x32_bf16(vf2, pfA, aA2, 0, 0, 0);
    aA3 = __builtin_amdgcn_mfma_f32_16x16x32_bf16(vf3, pfA, aA3, 0, 0, 0);
    aB0 = __builtin_amdgcn_mfma_f32_16x16x32_bf16(vf0, pfB, aB0, 0, 0, 0);
    aB1 = __builtin_amdgcn_mfma_f32_16x16x32_bf16(vf1, pfB, aB1, 0, 0, 0);
    aB2 = __builtin_amdgcn_mfma_f32_16x16x32_bf16(vf2, pfB, aB2, 0, 0, 0);
    aB3 = __builtin_amdgcn_mfma_f32_16x16x32_bf16(vf3, pfB, aB3, 0, 0, 0);

    kf0 = nk0; kf1 = nk1;
    vf0 = nv0; vf1 = nv1; vf2 = nv2; vf3 = nv3;
  }

  // full (this wave's m-range) row sums; every lane ends with l for n = q16
  lA += __shfl_xor(lA, 16); lA += __shfl_xor(lA, 32);
  lB += __shfl_xor(lB, 16); lB += __shfl_xor(lB, 32);

  // two-stage cross-wave (O,l) reduction: 8 waves -> 4 -> gather
  f32x4 aAs[4] = {aA0, aA1, aA2, aA3};
  f32x4 aBs[4] = {aB0, aB1, aB2, aB3};

  if (wave >= 4) {
    float* d = &buf[wave - 4][lane][0];
#pragma unroll
    for (int j = 0; j < 4; ++j)
#pragma unroll
      for (int r = 0; r < 4; ++r) {
        d[j * 4 + r]      = aAs[j][r];
        d[16 + j * 4 + r] = aBs[j][r];
      }
    d[32] = lA; d[33] = lB;
  }
  __syncthreads();
  if (wave < 4) {
    float* d = &buf[wave][lane][0];
#pragma unroll
    for (int j = 0; j < 4; ++j)
#pragma unroll
      for (int r = 0; r < 4; ++r) {
        aAs[j][r] += d[j * 4 + r];
        aBs[j][r] += d[16 + j * 4 + r];
      }
    lA += d[32]; lB += d[33];
#pragma unroll
    for (int j = 0; j < 4; ++j)
#pragma unroll
      for (int r = 0; r < 4; ++r) {
        d[j * 4 + r]      = aAs[j][r];
        d[16 + j * 4 + r] = aBs[j][r];
      }
    d[32] = lA; d[33] = lB;
  }
  __syncthreads();

  // gather: wave = qt*4 + cg; lane (q, n=q16) owns c = 16cg+4q+r, n = n0+16qt+q16
  const int qt = wave >> 2;
  const int cg = wave & 3;
  float fr[4] = {0.f, 0.f, 0.f, 0.f};
  float lt = 0.f;
#pragma unroll
  for (int w2 = 0; w2 < 4; ++w2) {
    lt += buf[w2][lane][32 + qt];
#pragma unroll
    for (int r = 0; r < 4; ++r) fr[r] += buf[w2][lane][qt * 16 + cg * 4 + r];
  }

  const float g = gamma[0];
  const float ginv = g / lt;           // l is lane-local: no shuffles
  const int nn = n0 + qt * 16 + q16;
#pragma unroll
  for (int r = 0; r < 4; ++r) {
    const int c = cg * 16 + quad * 4 + r;
    const size_t idx = ((size_t)(b * 64 + c)) * NSEQ + nn;
    out[idx] = fr[r] * ginv + x[idx];
  }
}

extern "C" void kernel_launch(void* const* d_in, const int* in_sizes, int n_in,
                              void* d_out, int out_size, void* d_ws, size_t ws_size,
                              hipStream_t stream) {
  (void)in_sizes; (void)n_in; (void)out_size; (void)ws_size;
  const float* x     = (const float*)d_in[0];
  const float* Wq    = (const float*)d_in[1];
  const float* bq    = (const float*)d_in[2];
  const float* Wk    = (const float*)d_in[3];
  const float* bk    = (const float*)d_in[4];
  const float* Wv    = (const float*)d_in[5];
  const float* bv    = (const float*)d_in[6];
  const float* gamma = (const float*)d_in[7];
  float* out = (float*)d_out;

  // workspace: Qb 256 KB | Kb 256 KB | Vb(tiled) 2 MB
  ushort_t* Qb = (ushort_t*)d_ws;
  ushort_t* Kb = (ushort_t*)((char*)d_ws + (256u << 10));
  ushort_t* Vb = (ushort_t*)((char*)d_ws + (512u << 10));

  hipLaunchKernelGGL(proj_kernel, dim3(256), dim3(256), 0, stream,
                     x, Wq, bq, Wk, bk, Wv, bv, Qb, Kb, Vb);
  hipLaunchKernelGGL(attn_kernel, dim3(512), dim3(512), 0, stream,
                     Qb, Kb, Vb, x, gamma, out);
}

// Round 6
// 96.100 us; speedup vs baseline: 1.1552x; 1.1552x over previous
//
#include <hip/hip_runtime.h>
#include <hip/hip_bf16.h>

// SelfAttention (B=4, C=64, N=4096, CQ=8), fp32 in/out.
// K1 proj (1024 blocks, k-chunked, no spills): Q -> compact bf16 [b][n][8]
//   PRE-SCALED by log2(e); K -> compact bf16 [b][n][8];
//   V -> bf16 TILED [b][m>>5][64c][m&31] (4 KB tiles, dense 1 KB frag loads).
// K2 attn (no LDS in loop, no scratch): S^T = Kperm^T*Q via mfma_16x16x32_bf16
//   where lane q16 loads K row 8*(q16>>2)+(q16&3); this row permutation makes
//   the exp'd C-fragment IDENTICAL to the B-operand fragment of the PV matmul
//   (O^T = V^T * P^T), so the C->A transform costs zero instructions.
//   All register moves use __builtin_bit_cast (no unions -> no scratch);
//   no explicit prefetch regs (16 waves/CU TLP hides L1/L2 latency) so the
//   live set fits the 128-VGPR budget of __launch_bounds__(512,4).
//   Unnormalized exp accumulate (|S|<~20: no max subtraction), lane-local
//   row-sum division, m split across 8 waves, two-stage (O,l) LDS reduction.

typedef __attribute__((ext_vector_type(8))) short short8;
typedef __attribute__((ext_vector_type(4))) float f32x4;
typedef __attribute__((ext_vector_type(4))) unsigned uint4v;
typedef unsigned short ushort_t;

#define NSEQ 4096
#define LOG2E 1.4426950408889634f

__device__ __forceinline__ unsigned pk_bf16(float lo, float hi) {
  const unsigned short a = __builtin_bit_cast(unsigned short, __float2bfloat16(lo));
  const unsigned short b = __builtin_bit_cast(unsigned short, __float2bfloat16(hi));
  return (unsigned)a | ((unsigned)b << 16);
}

__global__ __launch_bounds__(256, 4) void proj_kernel(
    const float* __restrict__ x,
    const float* __restrict__ Wq, const float* __restrict__ bq,
    const float* __restrict__ Wk, const float* __restrict__ bk,
    const float* __restrict__ Wv, const float* __restrict__ bv,
    ushort_t* __restrict__ Qb, ushort_t* __restrict__ Kb,
    ushort_t* __restrict__ Vb)
{
  const int tid  = threadIdx.x;
  const int lane = tid & 63;
  const int w    = __builtin_amdgcn_readfirstlane(tid >> 6);
  const int blk  = blockIdx.x;
  const int quarter = blk & 3;
  const int g    = (blk >> 2) & 63;
  const int b    = blk >> 8;
  const int n    = g * 64 + lane;

  const float* xb = x + (size_t)(b * 64) * NSEQ + n;
  const int co0 = quarter * 16 + w * 4;
  const float* w0 = Wv + (co0 + 0) * 64;
  const float* w1 = Wv + (co0 + 1) * 64;
  const float* w2 = Wv + (co0 + 2) * 64;
  const float* w3 = Wv + (co0 + 3) * 64;
  const int p = quarter * 4 + w;              // 0..7 -> q, 8..15 -> k
  const float* wr = (p < 8) ? (Wq + p * 64) : (Wk + (p - 8) * 64);
  float a0 = bv[co0 + 0], a1 = bv[co0 + 1], a2 = bv[co0 + 2], a3 = bv[co0 + 3];
  float aq = (p < 8) ? bq[p] : bk[p - 8];

  // k-chunked streaming: few live VGPRs, weight reads are s_loads
#pragma unroll
  for (int kc = 0; kc < 64; kc += 8) {
    float xv[8];
#pragma unroll
    for (int i = 0; i < 8; ++i) xv[i] = xb[(size_t)(kc + i) * NSEQ];
#pragma unroll
    for (int i = 0; i < 8; ++i) {
      const float xk = xv[i];
      a0 += w0[kc + i] * xk;
      a1 += w1[kc + i] * xk;
      a2 += w2[kc + i] * xk;
      a3 += w3[kc + i] * xk;
      aq += wr[kc + i] * xk;
    }
  }

  // V tiled store: tile (b, n>>5), row co, col n&31
  ushort_t* vt = Vb + ((size_t)(b * 128 + (n >> 5)) * 64 + co0) * 32 + (n & 31);
  vt[0]  = __builtin_bit_cast(ushort_t, __float2bfloat16(a0));
  vt[32] = __builtin_bit_cast(ushort_t, __float2bfloat16(a1));
  vt[64] = __builtin_bit_cast(ushort_t, __float2bfloat16(a2));
  vt[96] = __builtin_bit_cast(ushort_t, __float2bfloat16(a3));

  // Q pre-scaled by log2(e) so attn's exp is a bare v_exp_f32
  if (p < 8) aq *= LOG2E;
  ushort_t* qk = ((p < 8) ? Qb : Kb) + ((size_t)(b * NSEQ + n)) * 8 + (p & 7);
  *qk = __builtin_bit_cast(ushort_t, __float2bfloat16(aq));
}

__global__ __launch_bounds__(512, 4) void attn_kernel(
    const ushort_t* __restrict__ Qb, const ushort_t* __restrict__ Kb,
    const ushort_t* __restrict__ Vb, const float* __restrict__ x,
    const float* __restrict__ gamma, float* __restrict__ out)
{
  __shared__ float buf[4][64][36];   // staged (O,l) cross-wave reduction, 36 KB

  const int tid  = threadIdx.x;
  const int wave = __builtin_amdgcn_readfirstlane(tid >> 6);   // 0..7
  const int lane = tid & 63;
  const int q16  = lane & 15;
  const int quad = lane >> 4;
  const int blk  = blockIdx.x;
  const int b    = blk >> 7;
  const int n0   = (blk & 127) << 5;   // block's 32 queries
  const int mbase = wave << 9;         // this wave's 512-m range

  // Q B-frags (k>=8 zeroed so compact K loads raw: garbage*0 = 0)
  const short8 z8 = {0, 0, 0, 0, 0, 0, 0, 0};
  short8 qfA = *(const short8*)(Qb + ((size_t)(b * NSEQ + n0 + q16)) * 8);
  short8 qfB = *(const short8*)(Qb + ((size_t)(b * NSEQ + n0 + 16 + q16)) * 8);
  if (quad != 0) { qfA = z8; qfB = z8; }

  // K A-frag with the row permutation: lane q16 -> row 8*(q16>>2)+(q16&3)
  // => exp'd S^T C-frag IS the PV B-frag (k = 8*quad+j <-> m = 8*quad+j).
  const int mperm = 8 * (q16 >> 2) + (q16 & 3);
  const char* kbase = (const char*)(Kb + ((size_t)(b * NSEQ + mbase + mperm)) * 8);
  // V A-frag (V^T): A[row=c=q16][k=m=quad*8+j] from tiled [64c][32m] 4KB tiles
  const char* vbase = (const char*)(Vb + ((size_t)(b * 128 + (mbase >> 5)) * 64) * 32)
                      + q16 * 64 + quad * 16;

  // accumulators: aXj = O^T tile, D[c = 16j+4*quad+r][n = q16 (+16 for B)]
  f32x4 aA0 = {0.f, 0.f, 0.f, 0.f};
  f32x4 aA1 = aA0, aA2 = aA0, aA3 = aA0;
  f32x4 aB0 = aA0, aB1 = aA0, aB2 = aA0, aB3 = aA0;
  float lA = 0.f, lB = 0.f;

#pragma unroll 2
  for (int t = 0; t < 16; ++t) {
    const char* kp = kbase + (size_t)t * 512;    // 32 K rows * 16 B
    const char* vp = vbase + (size_t)t * 4096;   // 4 KB V tile
    const short8 kf0 = *(const short8*)(kp);         // rows {8q..8q+3}
    const short8 kf1 = *(const short8*)(kp + 64);    // rows {8q+4..8q+7}
    const short8 vf0 = *(const short8*)(vp);
    const short8 vf1 = *(const short8*)(vp + 1024);
    const short8 vf2 = *(const short8*)(vp + 2048);
    const short8 vf3 = *(const short8*)(vp + 3072);

    // S^T in log2 domain (Q pre-scaled): D[mperm][n]
    const f32x4 z = {0.f, 0.f, 0.f, 0.f};
    f32x4 s0 = __builtin_amdgcn_mfma_f32_16x16x32_bf16(kf0, qfA, z, 0, 0, 0);
    f32x4 s1 = __builtin_amdgcn_mfma_f32_16x16x32_bf16(kf1, qfA, z, 0, 0, 0);
    f32x4 s2 = __builtin_amdgcn_mfma_f32_16x16x32_bf16(kf0, qfB, z, 0, 0, 0);
    f32x4 s3 = __builtin_amdgcn_mfma_f32_16x16x32_bf16(kf1, qfB, z, 0, 0, 0);

    // unnormalized numerators; lane (quad, n) holds m = 8*quad..8*quad+7
    float pA0 = __builtin_amdgcn_exp2f(s0[0]);
    float pA1 = __builtin_amdgcn_exp2f(s0[1]);
    float pA2 = __builtin_amdgcn_exp2f(s0[2]);
    float pA3 = __builtin_amdgcn_exp2f(s0[3]);
    float pA4 = __builtin_amdgcn_exp2f(s1[0]);
    float pA5 = __builtin_amdgcn_exp2f(s1[1]);
    float pA6 = __builtin_amdgcn_exp2f(s1[2]);
    float pA7 = __builtin_amdgcn_exp2f(s1[3]);
    float pB0 = __builtin_amdgcn_exp2f(s2[0]);
    float pB1 = __builtin_amdgcn_exp2f(s2[1]);
    float pB2 = __builtin_amdgcn_exp2f(s2[2]);
    float pB3 = __builtin_amdgcn_exp2f(s2[3]);
    float pB4 = __builtin_amdgcn_exp2f(s3[0]);
    float pB5 = __builtin_amdgcn_exp2f(s3[1]);
    float pB6 = __builtin_amdgcn_exp2f(s3[2]);
    float pB7 = __builtin_amdgcn_exp2f(s3[3]);
    lA += ((pA0 + pA1) + (pA2 + pA3)) + ((pA4 + pA5) + (pA6 + pA7));
    lB += ((pB0 + pB1) + (pB2 + pB3)) + ((pB4 + pB5) + (pB6 + pB7));

    // pack pairs: register-to-register bit_cast (no union -> no scratch);
    // result IS the PV B-frag B[k=8*quad+j][n]
    const uint4v uA = {pk_bf16(pA0, pA1), pk_bf16(pA2, pA3),
                       pk_bf16(pA4, pA5), pk_bf16(pA6, pA7)};
    const uint4v uB = {pk_bf16(pB0, pB1), pk_bf16(pB2, pB3),
                       pk_bf16(pB4, pB5), pk_bf16(pB6, pB7)};
    const short8 pfA = __builtin_bit_cast(short8, uA);
    const short8 pfB = __builtin_bit_cast(short8, uB);

    // O^T[c][n] += V^T[c][m] * P^T[m][n]
    aA0 = __builtin_amdgcn_mfma_f32_16x16x32_bf16(vf0, pfA, aA0, 0, 0, 0);
    aA1 = __builtin_amdgcn_mfma_f32_16x16x32_bf16(vf1, pfA, aA1, 0, 0, 0);
    aA2 = __builtin_amdgcn_mfma_f32_16x16x32_bf16(vf2, pfA, aA2, 0, 0, 0);
    aA3 = __builtin_amdgcn_mfma_f32_16x16x32_bf16(vf3, pfA, aA3, 0, 0, 0);
    aB0 = __builtin_amdgcn_mfma_f32_16x16x32_bf16(vf0, pfB, aB0, 0, 0, 0);
    aB1 = __builtin_amdgcn_mfma_f32_16x16x32_bf16(vf1, pfB, aB1, 0, 0, 0);
    aB2 = __builtin_amdgcn_mfma_f32_16x16x32_bf16(vf2, pfB, aB2, 0, 0, 0);
    aB3 = __builtin_amdgcn_mfma_f32_16x16x32_bf16(vf3, pfB, aB3, 0, 0, 0);
  }

  // full (this wave's m-range) row sums; every lane ends with l for n = q16
  lA += __shfl_xor(lA, 16); lA += __shfl_xor(lA, 32);
  lB += __shfl_xor(lB, 16); lB += __shfl_xor(lB, 32);

  // two-stage cross-wave (O,l) reduction: 8 waves -> 4 -> gather
  f32x4 aAs[4] = {aA0, aA1, aA2, aA3};
  f32x4 aBs[4] = {aB0, aB1, aB2, aB3};

  if (wave >= 4) {
    float* d = &buf[wave - 4][lane][0];
#pragma unroll
    for (int j = 0; j < 4; ++j)
#pragma unroll
      for (int r = 0; r < 4; ++r) {
        d[j * 4 + r]      = aAs[j][r];
        d[16 + j * 4 + r] = aBs[j][r];
      }
    d[32] = lA; d[33] = lB;
  }
  __syncthreads();
  if (wave < 4) {
    float* d = &buf[wave][lane][0];
#pragma unroll
    for (int j = 0; j < 4; ++j)
#pragma unroll
      for (int r = 0; r < 4; ++r) {
        aAs[j][r] += d[j * 4 + r];
        aBs[j][r] += d[16 + j * 4 + r];
      }
    lA += d[32]; lB += d[33];
#pragma unroll
    for (int j = 0; j < 4; ++j)
#pragma unroll
      for (int r = 0; r < 4; ++r) {
        d[j * 4 + r]      = aAs[j][r];
        d[16 + j * 4 + r] = aBs[j][r];
      }
    d[32] = lA; d[33] = lB;
  }
  __syncthreads();

  // gather: wave = qt*4 + cg; lane (quad, q16) owns c = 16cg+4quad+r, n = n0+16qt+q16
  const int qt = wave >> 2;
  const int cg = wave & 3;
  float fr[4] = {0.f, 0.f, 0.f, 0.f};
  float lt = 0.f;
#pragma unroll
  for (int w2 = 0; w2 < 4; ++w2) {
    lt += buf[w2][lane][32 + qt];
#pragma unroll
    for (int r = 0; r < 4; ++r) fr[r] += buf[w2][lane][qt * 16 + cg * 4 + r];
  }

  const float ginv = gamma[0] / lt;    // l is lane-local: no shuffles
  const int nn = n0 + qt * 16 + q16;
#pragma unroll
  for (int r = 0; r < 4; ++r) {
    const int c = cg * 16 + quad * 4 + r;
    const size_t idx = ((size_t)(b * 64 + c)) * NSEQ + nn;
    out[idx] = fr[r] * ginv + x[idx];
  }
}

extern "C" void kernel_launch(void* const* d_in, const int* in_sizes, int n_in,
                              void* d_out, int out_size, void* d_ws, size_t ws_size,
                              hipStream_t stream) {
  (void)in_sizes; (void)n_in; (void)out_size; (void)ws_size;
  const float* x     = (const float*)d_in[0];
  const float* Wq    = (const float*)d_in[1];
  const float* bq    = (const float*)d_in[2];
  const float* Wk    = (const float*)d_in[3];
  const float* bk    = (const float*)d_in[4];
  const float* Wv    = (const float*)d_in[5];
  const float* bv    = (const float*)d_in[6];
  const float* gamma = (const float*)d_in[7];
  float* out = (float*)d_out;

  // workspace: Qb 256 KB | Kb 256 KB | Vb(tiled) 2 MB
  ushort_t* Qb = (ushort_t*)d_ws;
  ushort_t* Kb = (ushort_t*)((char*)d_ws + (256u << 10));
  ushort_t* Vb = (ushort_t*)((char*)d_ws + (512u << 10));

  hipLaunchKernelGGL(proj_kernel, dim3(1024), dim3(256), 0, stream,
                     x, Wq, bq, Wk, bk, Wv, bv, Qb, Kb, Vb);
  hipLaunchKernelGGL(attn_kernel, dim3(512), dim3(512), 0, stream,
                     Qb, Kb, Vb, x, gamma, out);
}

// Round 7
// 95.246 us; speedup vs baseline: 1.1656x; 1.0090x over previous
//
#include <hip/hip_runtime.h>
#include <hip/hip_bf16.h>

// SelfAttention (B=4, C=64, N=4096, CQ=8), fp32 in/out.
// K1 proj (1024 blocks, k-chunked, no spills): Q -> compact bf16 [b][n][8]
//   PRE-SCALED by log2(e); K -> compact bf16 [b][n][8];
//   V -> bf16 TILED [b][m>>5][64c][m&31] (4 KB tiles, dense 1 KB frag loads).
// K2 attn (no LDS in loop, no scratch): 64 queries/block (256 blocks) so each
//   full-V sweep is amortized over 2x the queries -> V L2 traffic halves vs
//   32q/block. S^T = Kperm^T*Q via mfma_16x16x32_bf16 where lane q16 loads
//   K row 8*(q16>>2)+(q16&3); this row permutation makes the exp'd C-frag
//   IDENTICAL to the PV B-operand frag (O^T = V^T * P^T): zero-instruction
//   C->A transform. bit_cast only (no unions -> no scratch). Unnormalized
//   exp accumulate (|S|<~20), lane-local row-sum division, m split across
//   8 waves, two-stage (O,l) LDS reduction (69-float stride, conflict-free).

typedef __attribute__((ext_vector_type(8))) short short8;
typedef __attribute__((ext_vector_type(4))) float f32x4;
typedef __attribute__((ext_vector_type(4))) unsigned uint4v;
typedef unsigned short ushort_t;

#define NSEQ 4096
#define LOG2E 1.4426950408889634f

__device__ __forceinline__ unsigned pk_bf16(float lo, float hi) {
  const unsigned short a = __builtin_bit_cast(unsigned short, __float2bfloat16(lo));
  const unsigned short b = __builtin_bit_cast(unsigned short, __float2bfloat16(hi));
  return (unsigned)a | ((unsigned)b << 16);
}

__global__ __launch_bounds__(256, 4) void proj_kernel(
    const float* __restrict__ x,
    const float* __restrict__ Wq, const float* __restrict__ bq,
    const float* __restrict__ Wk, const float* __restrict__ bk,
    const float* __restrict__ Wv, const float* __restrict__ bv,
    ushort_t* __restrict__ Qb, ushort_t* __restrict__ Kb,
    ushort_t* __restrict__ Vb)
{
  const int tid  = threadIdx.x;
  const int lane = tid & 63;
  const int w    = __builtin_amdgcn_readfirstlane(tid >> 6);
  const int blk  = blockIdx.x;
  const int quarter = blk & 3;
  const int g    = (blk >> 2) & 63;
  const int b    = blk >> 8;
  const int n    = g * 64 + lane;

  const float* xb = x + (size_t)(b * 64) * NSEQ + n;
  const int co0 = quarter * 16 + w * 4;
  const float* w0 = Wv + (co0 + 0) * 64;
  const float* w1 = Wv + (co0 + 1) * 64;
  const float* w2 = Wv + (co0 + 2) * 64;
  const float* w3 = Wv + (co0 + 3) * 64;
  const int p = quarter * 4 + w;              // 0..7 -> q, 8..15 -> k
  const float* wr = (p < 8) ? (Wq + p * 64) : (Wk + (p - 8) * 64);
  float a0 = bv[co0 + 0], a1 = bv[co0 + 1], a2 = bv[co0 + 2], a3 = bv[co0 + 3];
  float aq = (p < 8) ? bq[p] : bk[p - 8];

  // k-chunked streaming: few live VGPRs, weight reads are s_loads
#pragma unroll
  for (int kc = 0; kc < 64; kc += 8) {
    float xv[8];
#pragma unroll
    for (int i = 0; i < 8; ++i) xv[i] = xb[(size_t)(kc + i) * NSEQ];
#pragma unroll
    for (int i = 0; i < 8; ++i) {
      const float xk = xv[i];
      a0 += w0[kc + i] * xk;
      a1 += w1[kc + i] * xk;
      a2 += w2[kc + i] * xk;
      a3 += w3[kc + i] * xk;
      aq += wr[kc + i] * xk;
    }
  }

  // V tiled store: tile (b, n>>5), row co, col n&31
  ushort_t* vt = Vb + ((size_t)(b * 128 + (n >> 5)) * 64 + co0) * 32 + (n & 31);
  vt[0]  = __builtin_bit_cast(ushort_t, __float2bfloat16(a0));
  vt[32] = __builtin_bit_cast(ushort_t, __float2bfloat16(a1));
  vt[64] = __builtin_bit_cast(ushort_t, __float2bfloat16(a2));
  vt[96] = __builtin_bit_cast(ushort_t, __float2bfloat16(a3));

  // Q pre-scaled by log2(e) so attn's exp is a bare v_exp_f32
  if (p < 8) aq *= LOG2E;
  ushort_t* qk = ((p < 8) ? Qb : Kb) + ((size_t)(b * NSEQ + n)) * 8 + (p & 7);
  *qk = __builtin_bit_cast(ushort_t, __float2bfloat16(aq));
}

__global__ __launch_bounds__(512, 2) void attn_kernel(
    const ushort_t* __restrict__ Qb, const ushort_t* __restrict__ Kb,
    const ushort_t* __restrict__ Vb, const float* __restrict__ x,
    const float* __restrict__ gamma, float* __restrict__ out)
{
  __shared__ float buf[4][64][69];   // staged (O,l) reduction, 70.7 KB

  const int tid  = threadIdx.x;
  const int wave = __builtin_amdgcn_readfirstlane(tid >> 6);   // 0..7
  const int lane = tid & 63;
  const int q16  = lane & 15;
  const int quad = lane >> 4;
  const int blk  = blockIdx.x;
  const int b    = blk >> 6;
  const int n0   = (blk & 63) << 6;    // block's 64 queries
  const int mbase = wave << 9;         // this wave's 512-m range

  // Q B-frags for 4 q-subtiles (k>=8 zeroed so compact K loads raw)
  const short8 z8 = {0, 0, 0, 0, 0, 0, 0, 0};
  short8 qf[4];
#pragma unroll
  for (int qt = 0; qt < 4; ++qt) {
    qf[qt] = *(const short8*)(Qb + ((size_t)(b * NSEQ + n0 + qt * 16 + q16)) * 8);
    if (quad != 0) qf[qt] = z8;
  }

  // K A-frag with the row permutation: lane q16 -> row 8*(q16>>2)+(q16&3)
  // => exp'd S^T C-frag IS the PV B-frag (k = 8*quad+j <-> m = 8*quad+j).
  const int mperm = 8 * (q16 >> 2) + (q16 & 3);
  const char* kbase = (const char*)(Kb + ((size_t)(b * NSEQ + mbase + mperm)) * 8);
  // V A-frag (V^T): A[row=c=q16][k=m=quad*8+j] from tiled [64c][32m] 4KB tiles
  const char* vbase = (const char*)(Vb + ((size_t)(b * 128 + (mbase >> 5)) * 64) * 32)
                      + q16 * 64 + quad * 16;

  // accumulators: acc[qt][cf] = D[c=16cf+4quad+r][n=n0+16qt+q16]
  f32x4 acc[4][4];
#pragma unroll
  for (int qt = 0; qt < 4; ++qt)
#pragma unroll
    for (int cf = 0; cf < 4; ++cf) acc[qt][cf] = (f32x4){0.f, 0.f, 0.f, 0.f};
  float l[4] = {0.f, 0.f, 0.f, 0.f};

#pragma unroll 1
  for (int t = 0; t < 16; ++t) {
    const char* kp = kbase + (size_t)t * 512;    // 32 K rows * 16 B
    const char* vp = vbase + (size_t)t * 4096;   // 4 KB V tile
    const short8 kf0 = *(const short8*)(kp);         // rows {8q..8q+3}
    const short8 kf1 = *(const short8*)(kp + 64);    // rows {8q+4..8q+7}
    const short8 vf0 = *(const short8*)(vp);
    const short8 vf1 = *(const short8*)(vp + 1024);
    const short8 vf2 = *(const short8*)(vp + 2048);
    const short8 vf3 = *(const short8*)(vp + 3072);

#pragma unroll
    for (int qt = 0; qt < 4; ++qt) {
      // S^T in log2 domain (Q pre-scaled): D[mperm][n]
      const f32x4 z = {0.f, 0.f, 0.f, 0.f};
      f32x4 s0 = __builtin_amdgcn_mfma_f32_16x16x32_bf16(kf0, qf[qt], z, 0, 0, 0);
      f32x4 s1 = __builtin_amdgcn_mfma_f32_16x16x32_bf16(kf1, qf[qt], z, 0, 0, 0);

      // unnormalized numerators; lane (quad, n) holds m = 8*quad..8*quad+7
      const float p0 = __builtin_amdgcn_exp2f(s0[0]);
      const float p1 = __builtin_amdgcn_exp2f(s0[1]);
      const float p2 = __builtin_amdgcn_exp2f(s0[2]);
      const float p3 = __builtin_amdgcn_exp2f(s0[3]);
      const float p4 = __builtin_amdgcn_exp2f(s1[0]);
      const float p5 = __builtin_amdgcn_exp2f(s1[1]);
      const float p6 = __builtin_amdgcn_exp2f(s1[2]);
      const float p7 = __builtin_amdgcn_exp2f(s1[3]);
      l[qt] += ((p0 + p1) + (p2 + p3)) + ((p4 + p5) + (p6 + p7));

      // pack pairs: register bit_cast; result IS the PV B-frag B[k=8q+j][n]
      const uint4v u = {pk_bf16(p0, p1), pk_bf16(p2, p3),
                        pk_bf16(p4, p5), pk_bf16(p6, p7)};
      const short8 pf = __builtin_bit_cast(short8, u);

      // O^T[c][n] += V^T[c][m] * P^T[m][n]
      acc[qt][0] = __builtin_amdgcn_mfma_f32_16x16x32_bf16(vf0, pf, acc[qt][0], 0, 0, 0);
      acc[qt][1] = __builtin_amdgcn_mfma_f32_16x16x32_bf16(vf1, pf, acc[qt][1], 0, 0, 0);
      acc[qt][2] = __builtin_amdgcn_mfma_f32_16x16x32_bf16(vf2, pf, acc[qt][2], 0, 0, 0);
      acc[qt][3] = __builtin_amdgcn_mfma_f32_16x16x32_bf16(vf3, pf, acc[qt][3], 0, 0, 0);
    }
  }

  // full (this wave's m-range) row sums; lane-local for n = n0+16qt+q16
#pragma unroll
  for (int qt = 0; qt < 4; ++qt) {
    l[qt] += __shfl_xor(l[qt], 16);
    l[qt] += __shfl_xor(l[qt], 32);
  }

  // two-stage cross-wave (O,l) reduction: 8 waves -> 4 -> gather
  if (wave >= 4) {
    float* d = &buf[wave - 4][lane][0];
#pragma unroll
    for (int qt = 0; qt < 4; ++qt) {
#pragma unroll
      for (int cf = 0; cf < 4; ++cf)
#pragma unroll
        for (int r = 0; r < 4; ++r) d[qt * 16 + cf * 4 + r] = acc[qt][cf][r];
      d[64 + qt] = l[qt];
    }
  }
  __syncthreads();
  if (wave < 4) {
    float* d = &buf[wave][lane][0];
#pragma unroll
    for (int qt = 0; qt < 4; ++qt) {
#pragma unroll
      for (int cf = 0; cf < 4; ++cf)
#pragma unroll
        for (int r = 0; r < 4; ++r) {
          acc[qt][cf][r] += d[qt * 16 + cf * 4 + r];
          d[qt * 16 + cf * 4 + r] = acc[qt][cf][r];
        }
      l[qt] += d[64 + qt];
      d[64 + qt] = l[qt];
    }
  }
  __syncthreads();

  // gather: wave -> qt = wave>>1, cg pair = 2*(wave&1)+{0,1};
  // lane (quad, q16) owns c = 16cg+4quad+r, n = n0+16qt+q16
  const int qt = wave >> 1;
  const int cg0 = (wave & 1) * 2;
  float lt = 0.f;
#pragma unroll
  for (int w2 = 0; w2 < 4; ++w2) lt += buf[w2][lane][64 + qt];
  const float ginv = gamma[0] / lt;
  const int nn = n0 + qt * 16 + q16;

#pragma unroll
  for (int h = 0; h < 2; ++h) {
    const int cg = cg0 + h;
    float fr[4] = {0.f, 0.f, 0.f, 0.f};
#pragma unroll
    for (int w2 = 0; w2 < 4; ++w2)
#pragma unroll
      for (int r = 0; r < 4; ++r) fr[r] += buf[w2][lane][qt * 16 + cg * 4 + r];
#pragma unroll
    for (int r = 0; r < 4; ++r) {
      const int c = cg * 16 + quad * 4 + r;
      const size_t idx = ((size_t)(b * 64 + c)) * NSEQ + nn;
      out[idx] = fr[r] * ginv + x[idx];
    }
  }
}

extern "C" void kernel_launch(void* const* d_in, const int* in_sizes, int n_in,
                              void* d_out, int out_size, void* d_ws, size_t ws_size,
                              hipStream_t stream) {
  (void)in_sizes; (void)n_in; (void)out_size; (void)ws_size;
  const float* x     = (const float*)d_in[0];
  const float* Wq    = (const float*)d_in[1];
  const float* bq    = (const float*)d_in[2];
  const float* Wk    = (const float*)d_in[3];
  const float* bk    = (const float*)d_in[4];
  const float* Wv    = (const float*)d_in[5];
  const float* bv    = (const float*)d_in[6];
  const float* gamma = (const float*)d_in[7];
  float* out = (float*)d_out;

  // workspace: Qb 256 KB | Kb 256 KB | Vb(tiled) 2 MB
  ushort_t* Qb = (ushort_t*)d_ws;
  ushort_t* Kb = (ushort_t*)((char*)d_ws + (256u << 10));
  ushort_t* Vb = (ushort_t*)((char*)d_ws + (512u << 10));

  hipLaunchKernelGGL(proj_kernel, dim3(1024), dim3(256), 0, stream,
                     x, Wq, bq, Wk, bk, Wv, bv, Qb, Kb, Vb);
  hipLaunchKernelGGL(attn_kernel, dim3(256), dim3(512), 0, stream,
                     Qb, Kb, Vb, x, gamma, out);
}